// Round 13
// baseline (1763.931 us; speedup 1.0000x reference)
//
#include <hip/hip_runtime.h>
#include <stdint.h>

// ---------------- types & helpers ----------------
typedef __attribute__((ext_vector_type(4))) float    f32x4;
typedef __attribute__((ext_vector_type(8))) short    s16x8;
typedef __attribute__((ext_vector_type(4))) short    s16x4;
typedef __attribute__((ext_vector_type(4))) unsigned u32x4;
typedef __attribute__((ext_vector_type(8))) __bf16   bf16x8;

#define DEV __device__ __forceinline__

DEV float b2f(short h) {
  unsigned u = ((unsigned)(unsigned short)h) << 16;
  return __builtin_bit_cast(float, u);
}
DEV short f2b(float f) {
  unsigned u = __builtin_bit_cast(unsigned, f);
  u = (u + 0x7FFFu + ((u >> 16) & 1u)) >> 16;
  return (short)u;
}
DEV float fsig(float x) { return 1.0f / (1.0f + __expf(-x)); }
DEV float ftanh(float x) {
  x = fminf(fmaxf(x, -15.0f), 15.0f);
  float e = __expf(2.0f * x);
  return (e - 1.0f) / (e + 1.0f);
}
DEV float fsp(float x) { return (x > 20.0f) ? x : __logf(1.0f + __expf(x)); }

DEV f32x4 MFMA(s16x8 a, s16x8 b, f32x4 c) {
  return __builtin_amdgcn_mfma_f32_16x16x32_bf16(
      __builtin_bit_cast(bf16x8, a), __builtin_bit_cast(bf16x8, b), c, 0, 0, 0);
}
DEV void gload16(const void* g, void* l) {
  __builtin_amdgcn_global_load_lds(
      (const __attribute__((address_space(1))) unsigned*)g,
      (__attribute__((address_space(3))) unsigned*)l, 16, 0, 0);
}

// ---- cross-XCD coherent accesses via LLC: sc0 sc1 (bypass L1+L2) ----
DEV s16x8 ld16c(const short* p) {
  s16x8 r;
  asm volatile("global_load_dwordx4 %0, %1, off sc0 sc1" : "=v"(r) : "v"(p) : "memory");
  return r;
}
DEV void st8c(short* p, s16x4 v) {
  asm volatile("global_store_dwordx2 %0, %1, off sc0 sc1" :: "v"(p), "v"(v) : "memory");
}
DEV void stflagc(unsigned* p, unsigned v) {
  asm volatile("global_store_dword %0, %1, off sc0 sc1" :: "v"(p), "v"(v) : "memory");
}
// poll 32 member flags (128B contiguous) until min >= tgt; one vmcnt round per iter
DEV void poll32c(const unsigned* f, unsigned tgt) {
  unsigned gd = 0;
  for (;;) {
    u32x4 a0, a1, a2, a3, a4, a5, a6, a7;
    asm volatile("global_load_dwordx4 %0, %8, off sc0 sc1\n\t"
                 "global_load_dwordx4 %1, %8, off offset:16 sc0 sc1\n\t"
                 "global_load_dwordx4 %2, %8, off offset:32 sc0 sc1\n\t"
                 "global_load_dwordx4 %3, %8, off offset:48 sc0 sc1\n\t"
                 "global_load_dwordx4 %4, %8, off offset:64 sc0 sc1\n\t"
                 "global_load_dwordx4 %5, %8, off offset:80 sc0 sc1\n\t"
                 "global_load_dwordx4 %6, %8, off offset:96 sc0 sc1\n\t"
                 "global_load_dwordx4 %7, %8, off offset:112 sc0 sc1\n\t"
                 "s_waitcnt vmcnt(0)"
                 : "=v"(a0), "=v"(a1), "=v"(a2), "=v"(a3),
                   "=v"(a4), "=v"(a5), "=v"(a6), "=v"(a7)
                 : "v"(f) : "memory");
    unsigned m = a0[0];
#define MIN4(x) { m = x[0] < m ? x[0] : m; m = x[1] < m ? x[1] : m; \
                  m = x[2] < m ? x[2] : m; m = x[3] < m ? x[3] : m; }
    MIN4(a0) MIN4(a1) MIN4(a2) MIN4(a3) MIN4(a4) MIN4(a5) MIN4(a6) MIN4(a7)
#undef MIN4
    if (m >= tgt) return;
    if (++gd > (1u << 18)) return;  // deadlock escape; never hit normally
  }
}

// flag init through the coherent path (hipMemset's cached zeros can evict OVER flags)
__global__ void k_initf(unsigned* __restrict__ f) {
  stflagc(f + threadIdx.x * 3, 0u);
  stflagc(f + threadIdx.x * 3 + 1, 0u);
  stflagc(f + threadIdx.x * 3 + 2, 0u);
}

// ---------------- fp32 -> bf16 converts ----------------
__global__ void k_f2b(const float* __restrict__ s, short* __restrict__ d, int n) {
  int i = (blockIdx.x * 256 + threadIdx.x) * 4;
  if (i >= n) return;
  float4 v = *(const float4*)(s + i);
  s16x4 o; o[0] = f2b(v.x); o[1] = f2b(v.y); o[2] = f2b(v.z); o[3] = f2b(v.w);
  *(s16x4*)(d + i) = o;
}
__global__ void k_f2bs(const float* __restrict__ s, short* __restrict__ d,
                       int cols, int sstr, int soff, int total) {
  int i = (blockIdx.x * 256 + threadIdx.x) * 4;
  if (i >= total) return;
  int r = i / cols, c = i - r * cols;
  float4 v = *(const float4*)(s + (size_t)r * sstr + soff + c);
  s16x4 o; o[0] = f2b(v.x); o[1] = f2b(v.y); o[2] = f2b(v.z); o[3] = f2b(v.w);
  *(s16x4*)(d + i) = o;
}
// merged decoder weights W_dec[2048][512]
__global__ void k_build_dec(const float* __restrict__ Whh, const float* __restrict__ Wih,
                            short* __restrict__ out) {
  int i = (blockIdx.x * 256 + threadIdx.x) * 4;
  if (i >= 1048576) return;
  int r = i >> 9, c = i & 511;
  float4 v;
  if (r < 1024) {
    float4 a = *(const float4*)(Whh + (size_t)r * 512 + c);
    float4 b = *(const float4*)(Wih + (size_t)r * 768 + 256 + c);
    v = make_float4(a.x + b.x, a.y + b.y, a.z + b.z, a.w + b.w);
  } else if (r < 1536) {
    v = *(const float4*)(Wih + (size_t)r * 768 + 256 + c);
  } else {
    v = *(const float4*)(Whh + (size_t)(r - 512) * 512 + c);
  }
  s16x4 o; o[0] = f2b(v.x); o[1] = f2b(v.y); o[2] = f2b(v.z); o[3] = f2b(v.w);
  *(s16x4*)(out + i) = o;
}

// ---------------- generic bf16 MFMA GEMM, 128x128 tile, BK=64 ----------------
template <int EPI>
__global__ __launch_bounds__(256) void kgemm(
    const short* __restrict__ A, const short* __restrict__ W,
    const float* __restrict__ bias, float* __restrict__ outF,
    short* __restrict__ outB, int M, int N, int K) {
  __shared__ short lA[8192];
  __shared__ short lB[8192];
  const int tid = threadIdx.x, lane = tid & 63, wid = tid >> 6;
  const int l15 = lane & 15, lq = lane >> 4;
  const int m0 = blockIdx.x * 128, n0 = blockIdx.y * 128;
  const int wr2 = wid >> 1, wc2 = wid & 1;
  const f32x4 vz = {0.f, 0.f, 0.f, 0.f};
  f32x4 acc[4][4];
#pragma unroll
  for (int i = 0; i < 4; ++i)
#pragma unroll
    for (int j = 0; j < 4; ++j) acc[i][j] = vz;
  const int Kb = K * 2;
  const int nkt = K >> 6;
  const int srow = lane >> 3, sk = (lane & 7) * 16;
  const char* gA = (const char*)A;
  const char* gW = (const char*)W;
  for (int kt = 0; kt < nkt; ++kt) {
    __syncthreads();
#pragma unroll
    for (int i = 0; i < 4; ++i) {
      const int c = wid * 4 + i;
      gload16(gA + (size_t)(m0 + c * 8 + srow) * Kb + kt * 128 + sk, (char*)lA + c * 1024);
      gload16(gW + (size_t)(n0 + c * 8 + srow) * Kb + kt * 128 + sk, (char*)lB + c * 1024);
    }
    __syncthreads();
#pragma unroll
    for (int kc = 0; kc < 2; ++kc) {
      s16x8 af[4], bf[4];
#pragma unroll
      for (int mt = 0; mt < 4; ++mt)
        af[mt] = *(const s16x8*)((const char*)lA + (wr2 * 64 + mt * 16 + l15) * 128 + kc * 64 + lq * 16);
#pragma unroll
      for (int nt = 0; nt < 4; ++nt)
        bf[nt] = *(const s16x8*)((const char*)lB + (wc2 * 64 + nt * 16 + l15) * 128 + kc * 64 + lq * 16);
#pragma unroll
      for (int mt = 0; mt < 4; ++mt)
#pragma unroll
        for (int nt = 0; nt < 4; ++nt)
          acc[mt][nt] = MFMA(af[mt], bf[nt], acc[mt][nt]);
    }
  }
#pragma unroll
  for (int mt = 0; mt < 4; ++mt) {
#pragma unroll
    for (int nt = 0; nt < 4; ++nt) {
      const int col = n0 + wc2 * 64 + nt * 16 + l15;
      const int rl = wr2 * 64 + mt * 16 + lq * 4;
      const int row = m0 + rl;
      const float bv = bias ? bias[col] : 0.f;
      if (EPI == 0) {
#pragma unroll
        for (int d = 0; d < 4; ++d) outF[(size_t)(row + d) * N + col] = acc[mt][nt][d] + bv;
      } else if (EPI == 1) {
#pragma unroll
        for (int d = 0; d < 4; ++d) {
          float v = acc[mt][nt][d] + bv;
          v = v > 0.f ? v : 0.f;
          outB[(size_t)(row + d) * N + col] = f2b(v);
        }
      } else if (EPI == 2) {
        s16x4 pk;
#pragma unroll
        for (int d = 0; d < 4; ++d) pk[d] = f2b(acc[mt][nt][d] + bv);
        *(s16x4*)(outB + ((size_t)blockIdx.x * N + col) * 128 + rl) = pk;
      } else {
#pragma unroll
        for (int d = 0; d < 4; ++d) {
          float v = ftanh(acc[mt][nt][d] + bv);
          outF[(size_t)(row + d) * N + col] = v;
          outB[(size_t)(row + d) * N + col] = f2b(v);
        }
      }
    }
  }
}

// ---------------- persistent encoder scan (per-wave flags, no barriers) ----------------
// 128 WGs x 256 thr. WG w: gru=w>>6, rr=w&63, bg=rr>>3 (16 batches), cw=rr&7.
// Wave wid 0..3: cols J0=(cw*4+wid)*16. Sync group (gru,bg): 32 wave-flags.
// hB per gru: [2 parity][64 blk][128 b][8] bf16.
DEV void enc_xp_load(const short* xpT, int tt, int J0, int lq, int b,
                     short xv[3][4]) {
  const short* xb = xpT + (size_t)tt * 196608;
#pragma unroll
  for (int g = 0; g < 3; ++g)
#pragma unroll
    for (int d = 0; d < 4; ++d)
      xv[g][d] = xb[(size_t)(g * 512 + J0 + lq * 4 + d) * 128 + b];
}

__global__ __launch_bounds__(256, 1) void enc_scan(
    const short* __restrict__ xpTf, const short* __restrict__ xpTb,
    const short* __restrict__ Whf, const short* __restrict__ Whb,
    const float* __restrict__ bhf, const float* __restrict__ bhb,
    short* __restrict__ hB, short* __restrict__ ench,
    unsigned* __restrict__ flags) {
  const int tid = threadIdx.x, lane = tid & 63, wid = tid >> 6;
  const int l15 = lane & 15, lq = lane >> 4;
  const int w = blockIdx.x;
  const int gru = w >> 6, rr = w & 63, bg = rr >> 3, cw = rr & 7;
  const int J0 = (cw * 4 + wid) * 16, b0 = bg * 16;
  const int b = b0 + l15;
  const short* Wg = gru ? Whb : Whf;
  const float* bb = gru ? bhb : bhf;
  const short* xpT = gru ? xpTb : xpTf;
  short* hBg = hB + (size_t)gru * 131072;
  unsigned* gfl = flags + (gru * 8 + bg) * 32;   // 32 wave-flags per group
  const int myfl = cw * 4 + wid;
  const f32x4 vz = {0.f, 0.f, 0.f, 0.f};

  s16x8 wfr[3][16];
#pragma unroll
  for (int g = 0; g < 3; ++g) {
    const short* wrp = Wg + (size_t)(g * 512 + J0 + l15) * 512 + lq * 8;
#pragma unroll
    for (int kc = 0; kc < 16; ++kc) wfr[g][kc] = *(const s16x8*)(wrp + kc * 32);
  }
  float bi[3][4];
#pragma unroll
  for (int g = 0; g < 3; ++g)
#pragma unroll
    for (int d = 0; d < 4; ++d) bi[g][d] = bb[g * 512 + J0 + lq * 4 + d];
  float hpv[4];
#pragma unroll
  for (int d = 0; d < 4; ++d) hpv[d] = 0.f;

  short xpv[3][4];
  enc_xp_load(xpT, gru ? 191 : 0, J0, lq, b, xpv);
  const int chb = J0 + lq * 4;

  // ---- t = 0 (peeled: h=0 -> acc=0) ----
  {
    s16x4 pk;
#pragma unroll
    for (int d = 0; d < 4; ++d) {
      float rg = fsig(b2f(xpv[0][d]) + bi[0][d]);
      float zg = fsig(b2f(xpv[1][d]) + bi[1][d]);
      float nn = ftanh(b2f(xpv[2][d]) + rg * bi[2][d]);
      float hv = (1.f - zg) * nn;
      hpv[d] = hv;
      pk[d] = f2b(hv);
    }
    st8c(hBg + (((size_t)((chb >> 3) * 128 + b)) << 3) + (chb & 7), pk);
    asm volatile("s_waitcnt vmcnt(0)" ::: "memory");
    if (lane == 0) stflagc(gfl + myfl, 1u);
    enc_xp_load(xpT, gru ? 190 : 1, J0, lq, b, xpv);  // xp(1), lands during poll
  }

  for (int t = 1; t < 192; ++t) {
    poll32c(gfl, (unsigned)t);
    s16x8 hb[16];
    const short* hsrc = hBg + ((t + 1) & 1) * 65536;
#pragma unroll
    for (int kc = 0; kc < 16; ++kc)
      hb[kc] = ld16c(hsrc + ((size_t)((kc * 4 + lq) * 128 + b) << 3));
    asm volatile("s_waitcnt vmcnt(0)" ::: "memory");
    __builtin_amdgcn_sched_barrier(0);
    f32x4 acc[3];
#pragma unroll
    for (int g = 0; g < 3; ++g) acc[g] = vz;
#pragma unroll
    for (int kc = 0; kc < 16; ++kc)
#pragma unroll
      for (int g = 0; g < 3; ++g) acc[g] = MFMA(wfr[g][kc], hb[kc], acc[g]);
    short* hdst = hBg + (t & 1) * 65536;
    s16x4 pk;
#pragma unroll
    for (int d = 0; d < 4; ++d) {
      float rg = fsig(b2f(xpv[0][d]) + acc[0][d] + bi[0][d]);
      float zg = fsig(b2f(xpv[1][d]) + acc[1][d] + bi[1][d]);
      float nn = ftanh(b2f(xpv[2][d]) + rg * (acc[2][d] + bi[2][d]));
      float hv = (1.f - zg) * nn + zg * hpv[d];
      hpv[d] = hv;
      pk[d] = f2b(hv);
    }
    st8c(hdst + (((size_t)((chb >> 3) * 128 + b)) << 3) + (chb & 7), pk);
    if (t == 191) *(s16x4*)(ench + (size_t)gru * 65536 + (size_t)b * 512 + chb) = pk;
    // per-wave drain + per-wave flag: no barrier, no cross-wave coupling
    asm volatile("s_waitcnt vmcnt(0)" ::: "memory");
    if (lane == 0) stflagc(gfl + myfl, (unsigned)(t + 1));
    if (t < 191) {
      const int tp = t + 1;
      enc_xp_load(xpT, gru ? (191 - tp) : tp, J0, lq, b, xpv);  // overlaps next poll
    }
  }
}

// ---------------- persistent decoder scan (merged weights; per-wave flags) ----------------
// 64 WGs x 256 thr. bg = w>>3 (16 batches), m = w&7 (64 cols). 4 waves/WG.
// W_dec rows: [0..511]=merged r, [512..1023]=merged z, [1024..1535]=Ws_n, [1536..2047]=Whh_n.
__global__ __launch_bounds__(256, 1) void dec_scan(
    const short* __restrict__ zpT, const short* __restrict__ Wd,
    const float* __restrict__ bhd, const float* __restrict__ pre0,
    const float* __restrict__ h0f, short* __restrict__ hB,
    short* __restrict__ Hs, unsigned* __restrict__ flags) {
  const int tid = threadIdx.x, lane = tid & 63, wid = tid >> 6;
  const int l15 = lane & 15, lq = lane >> 4;
  const int w = blockIdx.x;
  const int bg = w >> 3, m = w & 7;
  unsigned* gfl = flags + 512 + bg * 32;   // 32 wave-flags per group
  const int myfl = m * 4 + wid;
  const int J0 = (m * 4 + wid) * 16, b0 = bg * 16;
  const int b = b0 + l15;
  const f32x4 vz = {0.f, 0.f, 0.f, 0.f};

  s16x8 wfr[4][16];
#pragma unroll
  for (int g = 0; g < 4; ++g) {
    const short* wrp = Wd + (size_t)(g * 512 + J0 + l15) * 512 + lq * 8;
#pragma unroll
    for (int kc = 0; kc < 16; ++kc) wfr[g][kc] = *(const s16x8*)(wrp + kc * 32);
  }
  float bi[3][4];
#pragma unroll
  for (int g = 0; g < 3; ++g)
#pragma unroll
    for (int d = 0; d < 4; ++d) bi[g][d] = bhd[g * 512 + J0 + lq * 4 + d];
  short zpv[3][4];
#pragma unroll
  for (int g = 0; g < 3; ++g)
#pragma unroll
    for (int d = 0; d < 4; ++d)
      zpv[g][d] = zpT[(size_t)(g * 512 + J0 + lq * 4 + d) * 128 + b];
  float hpv[4];
#pragma unroll
  for (int d = 0; d < 4; ++d) hpv[d] = h0f[(size_t)b * 512 + J0 + lq * 4 + d];
  const int chb = J0 + lq * 4;

  // ---- t = 0 (peeled: s=0, h=dec_h0; pre0 = h0@Whh_d.T + bhh_d) ----
  {
    s16x4 pk;
#pragma unroll
    for (int d = 0; d < 4; ++d) {
      float p0 = pre0[(size_t)b * 1536 + 0 * 512 + J0 + lq * 4 + d];
      float p1 = pre0[(size_t)b * 1536 + 1 * 512 + J0 + lq * 4 + d];
      float p2 = pre0[(size_t)b * 1536 + 2 * 512 + J0 + lq * 4 + d];
      float rg = fsig(b2f(zpv[0][d]) + p0);
      float zg = fsig(b2f(zpv[1][d]) + p1);
      float nn = ftanh(b2f(zpv[2][d]) + rg * p2);
      float hv = (1.f - zg) * nn + zg * hpv[d];
      hpv[d] = hv;
      pk[d] = f2b(hv);
    }
    st8c(hB + (((size_t)((chb >> 3) * 128 + b)) << 3) + (chb & 7), pk);
    asm volatile("s_waitcnt vmcnt(0)" ::: "memory");
    if (lane == 0) stflagc(gfl + myfl, 1u);
    *(s16x4*)(Hs + (size_t)b * 512 + chb) = pk;  // side-store, off the chain
  }

  for (int t = 1; t < 192; ++t) {
    poll32c(gfl, (unsigned)t);
    s16x8 hb[16];
    const short* hsrc = hB + ((t + 1) & 1) * 65536;
#pragma unroll
    for (int kc = 0; kc < 16; ++kc)
      hb[kc] = ld16c(hsrc + ((size_t)((kc * 4 + lq) * 128 + b) << 3));
    asm volatile("s_waitcnt vmcnt(0)" ::: "memory");
    __builtin_amdgcn_sched_barrier(0);
    f32x4 acc[4];
#pragma unroll
    for (int g = 0; g < 4; ++g) acc[g] = vz;
#pragma unroll
    for (int kc = 0; kc < 16; ++kc)
#pragma unroll
      for (int g = 0; g < 4; ++g) acc[g] = MFMA(wfr[g][kc], hb[kc], acc[g]);
    short* hdst = hB + (t & 1) * 65536;
    s16x4 pk;
#pragma unroll
    for (int d = 0; d < 4; ++d) {
      float rg = fsig(b2f(zpv[0][d]) + acc[0][d] + bi[0][d]);
      float zg = fsig(b2f(zpv[1][d]) + acc[1][d] + bi[1][d]);
      float nn = ftanh(b2f(zpv[2][d]) + acc[2][d] + rg * (acc[3][d] + bi[2][d]));
      float hv = (1.f - zg) * nn + zg * hpv[d];
      hpv[d] = hv;
      pk[d] = f2b(hv);
    }
    st8c(hdst + (((size_t)((chb >> 3) * 128 + b)) << 3) + (chb & 7), pk);
    asm volatile("s_waitcnt vmcnt(0)" ::: "memory");
    if (lane == 0) stflagc(gfl + myfl, (unsigned)(t + 1));
    *(s16x4*)(Hs + (size_t)(t * 128 + b) * 512 + chb) = pk;  // off the chain
  }
}

// ---------------- latent elementwise ----------------
__global__ void k_latent(const float* __restrict__ tmp, const float* __restrict__ b_mean,
                         const float* __restrict__ b_std, const float* __restrict__ eps_z,
                         float* __restrict__ out, short* __restrict__ zexp) {
  int i = blockIdx.x * 256 + threadIdx.x;
  if (i >= 32768) return;
  int c = i & 127, b = (i >> 7) & 127, g = i >> 14;
  float mp = tmp[(size_t)(g * 128 + b) * 256 + c] + b_mean[c];
  float sp = fsp(tmp[(size_t)(g * 128 + b) * 256 + 128 + c] + b_std[c]);
  float zv = eps_z[i] * sp + mp;
  out[i] = mp;
  out[32768 + i] = sp;
  out[65536 + i] = zv;
  zexp[b * 256 + g * 128 + c] = f2b(zv);
}

// ---------------- outputs elementwise ----------------
__global__ void k_preds(const float* __restrict__ tmp2, const float* __restrict__ b_dm,
                        const float* __restrict__ b_ds, const float* __restrict__ eps_y,
                        float* __restrict__ out) {
  int j = blockIdx.x * 256 + threadIdx.x;
  if (j >= 1572864) return;
  int c = j & 63;
  int row = j >> 6;
  float m = fsp(tmp2[(size_t)row * 128 + c] + b_dm[c]);
  float st = fsp(tmp2[(size_t)row * 128 + 64 + c] + b_ds[c]);
  out[98304 + j] = eps_y[j] * st + m;
  out[1671168 + j] = m;
  out[3244032 + j] = st;
}

// ---------------- launch ----------------
extern "C" void kernel_launch(void* const* d_in, const int* in_sizes, int n_in,
                              void* d_out, int out_size, void* d_ws, size_t ws_size,
                              hipStream_t stream) {
  (void)in_sizes; (void)n_in; (void)out_size; (void)ws_size;
  const float* x      = (const float*)d_in[0];
  const float* eps_z  = (const float*)d_in[2];
  const float* eps_y  = (const float*)d_in[3];
  const float* W_phi1 = (const float*)d_in[4];
  const float* b_phi1 = (const float*)d_in[5];
  const float* W_phi2 = (const float*)d_in[6];
  const float* b_phi2 = (const float*)d_in[7];
  const float* Wih_ef = (const float*)d_in[8];
  const float* bih_ef = (const float*)d_in[9];
  const float* Whh_ef = (const float*)d_in[10];
  const float* bhh_ef = (const float*)d_in[11];
  const float* Wih_eb = (const float*)d_in[12];
  const float* bih_eb = (const float*)d_in[13];
  const float* Whh_eb = (const float*)d_in[14];
  const float* bhh_eb = (const float*)d_in[15];
  const float* W_mean = (const float*)d_in[16];
  const float* b_mean = (const float*)d_in[17];
  const float* W_std  = (const float*)d_in[18];
  const float* b_std  = (const float*)d_in[19];
  const float* W_fh   = (const float*)d_in[20];
  const float* b_fh   = (const float*)d_in[21];
  const float* Wih_d  = (const float*)d_in[22];
  const float* bih_d  = (const float*)d_in[23];
  const float* Whh_d  = (const float*)d_in[24];
  const float* bhh_d  = (const float*)d_in[25];
  const float* W_dm   = (const float*)d_in[26];
  const float* b_dm   = (const float*)d_in[27];
  const float* W_ds   = (const float*)d_in[28];
  const float* b_ds   = (const float*)d_in[29];
  float* out = (float*)d_out;
  char* ws = (char*)d_ws;

  short* x16  = (short*)(ws + 0);
  short* C1   = (short*)(ws + 6291456);
  short* Hs   = (short*)(ws + 0);
  short* phi  = (short*)(ws + 31457280);
  float* tmp2 = (float*)(ws + 31457280);
  short* xpf  = (short*)(ws + 56623104);
  short* xpb  = (short*)(ws + 132120576);
  short* w_dec = (short*)(ws + 56623104);
  float* pre0F = (float*)(ws + 58720256);
  short* h0b   = (short*)(ws + 59506688);
  char*  wb   = ws + 207618048;
  short* w_phi1_16 = (short*)(wb + 0);
  short* w_phi2_16 = (short*)(wb + 131072);
  short* w_ihef = (short*)(wb + 655360);
  short* w_hhef = (short*)(wb + 2228224);
  short* w_iheb = (short*)(wb + 3801088);
  short* w_hheb = (short*)(wb + 5373952);
  short* w_ms   = (short*)(wb + 6946816);
  short* w_fh   = (short*)(wb + 7208960);
  short* w_z    = (short*)(wb + 7471104);
  short* w_hhd  = (short*)(wb + 9830400);
  short* w_out  = (short*)(wb + 11403264);
  short* hBe   = (short*)(ws + 219152384);
  short* ench  = (short*)(ws + 219676672);
  float* tmpms = (float*)(ws + 219938816);
  short* zexp  = (short*)(ws + 220200960);
  float* h0f   = (float*)(ws + 220266496);
  short* hBd   = (short*)(ws + 220528640);
  short* zpT   = (short*)(ws + 220790784);
  unsigned* flags  = (unsigned*)(ws + 221184000);   // enc: [0..511], dec: [512..767]

  k_initf<<<1, 256, 0, stream>>>(flags);

  k_f2b<<<3072, 256, 0, stream>>>(x, x16, 3145728);
  k_f2b<<<64,   256, 0, stream>>>(W_phi1, w_phi1_16, 65536);
  k_f2b<<<256,  256, 0, stream>>>(W_phi2, w_phi2_16, 262144);
  k_f2b<<<768,  256, 0, stream>>>(Wih_ef, w_ihef, 786432);
  k_f2b<<<768,  256, 0, stream>>>(Whh_ef, w_hhef, 786432);
  k_f2b<<<768,  256, 0, stream>>>(Wih_eb, w_iheb, 786432);
  k_f2b<<<768,  256, 0, stream>>>(Whh_eb, w_hheb, 786432);
  k_f2b<<<64,   256, 0, stream>>>(W_mean, w_ms, 65536);
  k_f2b<<<64,   256, 0, stream>>>(W_std,  w_ms + 65536, 65536);
  k_f2b<<<128,  256, 0, stream>>>(W_fh, w_fh, 131072);
  k_f2b<<<768,  256, 0, stream>>>(Whh_d, w_hhd, 786432);
  k_f2b<<<32,   256, 0, stream>>>(W_dm, w_out, 32768);
  k_f2b<<<32,   256, 0, stream>>>(W_ds, w_out + 32768, 32768);
  k_f2bs<<<384, 256, 0, stream>>>(Wih_d, w_z, 256, 768, 0, 393216);

  kgemm<1><<<dim3(192, 4), 256, 0, stream>>>(x16, w_phi1_16, b_phi1, (float*)nullptr, C1, 24576, 512, 128);
  kgemm<1><<<dim3(192, 4), 256, 0, stream>>>(C1, w_phi2_16, b_phi2, (float*)nullptr, phi, 24576, 512, 512);
  kgemm<2><<<dim3(192, 12), 256, 0, stream>>>(phi, w_ihef, bih_ef, (float*)nullptr, xpf, 24576, 1536, 512);
  kgemm<2><<<dim3(192, 12), 256, 0, stream>>>(phi, w_iheb, bih_eb, (float*)nullptr, xpb, 24576, 1536, 512);
  enc_scan<<<128, 256, 0, stream>>>(xpf, xpb, w_hhef, w_hheb, bhh_ef, bhh_eb, hBe, ench, flags);
  // decoder prep (xpf region now dead)
  k_build_dec<<<1024, 256, 0, stream>>>(Whh_d, Wih_d, w_dec);
  kgemm<0><<<dim3(2, 2), 256, 0, stream>>>(ench, w_ms, (const float*)nullptr, tmpms, (short*)nullptr, 256, 256, 512);
  k_latent<<<128, 256, 0, stream>>>(tmpms, b_mean, b_std, eps_z, out, zexp);
  kgemm<3><<<dim3(1, 4), 256, 0, stream>>>(zexp, w_fh, b_fh, h0f, h0b, 128, 512, 256);
  kgemm<2><<<dim3(1, 12), 256, 0, stream>>>(zexp, w_z, bih_d, (float*)nullptr, zpT, 128, 1536, 256);
  kgemm<0><<<dim3(1, 12), 256, 0, stream>>>(h0b, w_hhd, bhh_d, pre0F, (short*)nullptr, 128, 1536, 512);
  dec_scan<<<64, 256, 0, stream>>>(zpT, w_dec, bhh_d, pre0F, h0f, hBd, Hs, flags);
  kgemm<0><<<dim3(192, 1), 256, 0, stream>>>(Hs, w_out, (const float*)nullptr, tmp2, (short*)nullptr, 24576, 128, 512);
  k_preds<<<6144, 256, 0, stream>>>(tmp2, b_dm, b_ds, eps_y, out);
}

// Round 14
// 1645.714 us; speedup vs baseline: 1.0718x; 1.0718x over previous
//
#include <hip/hip_runtime.h>
#include <stdint.h>

// ---------------- types & helpers ----------------
typedef __attribute__((ext_vector_type(4))) float    f32x4;
typedef __attribute__((ext_vector_type(8))) short    s16x8;
typedef __attribute__((ext_vector_type(4))) short    s16x4;
typedef __attribute__((ext_vector_type(4))) unsigned u32x4;
typedef __attribute__((ext_vector_type(8))) __bf16   bf16x8;

#define DEV __device__ __forceinline__

DEV float b2f(short h) {
  unsigned u = ((unsigned)(unsigned short)h) << 16;
  return __builtin_bit_cast(float, u);
}
DEV short f2b(float f) {
  unsigned u = __builtin_bit_cast(unsigned, f);
  u = (u + 0x7FFFu + ((u >> 16) & 1u)) >> 16;
  return (short)u;
}
DEV float fsig(float x) { return 1.0f / (1.0f + __expf(-x)); }
DEV float ftanh(float x) {
  x = fminf(fmaxf(x, -15.0f), 15.0f);
  float e = __expf(2.0f * x);
  return (e - 1.0f) / (e + 1.0f);
}
DEV float fsp(float x) { return (x > 20.0f) ? x : __logf(1.0f + __expf(x)); }

DEV f32x4 MFMA(s16x8 a, s16x8 b, f32x4 c) {
  return __builtin_amdgcn_mfma_f32_16x16x32_bf16(
      __builtin_bit_cast(bf16x8, a), __builtin_bit_cast(bf16x8, b), c, 0, 0, 0);
}
DEV void gload16(const void* g, void* l) {
  __builtin_amdgcn_global_load_lds(
      (const __attribute__((address_space(1))) unsigned*)g,
      (__attribute__((address_space(3))) unsigned*)l, 16, 0, 0);
}

// ---- cross-XCD coherent accesses via LLC: sc0 sc1 (bypass L1+L2) ----
DEV s16x8 ld16c(const short* p) {
  s16x8 r;
  asm volatile("global_load_dwordx4 %0, %1, off sc0 sc1" : "=v"(r) : "v"(p) : "memory");
  return r;
}
DEV void st8c(short* p, s16x4 v) {
  asm volatile("global_store_dwordx2 %0, %1, off sc0 sc1" :: "v"(p), "v"(v) : "memory");
}
DEV void stflagc(unsigned* p, unsigned v) {
  asm volatile("global_store_dword %0, %1, off sc0 sc1" :: "v"(p), "v"(v) : "memory");
}
// poll 8 flag dwords until min >= tgt
DEV void poll8c(const unsigned* f, unsigned tgt) {
  unsigned gd = 0;
  for (;;) {
    u32x4 a, b;
    asm volatile("global_load_dwordx4 %0, %2, off sc0 sc1\n\t"
                 "global_load_dwordx4 %1, %2, off offset:16 sc0 sc1\n\t"
                 "s_waitcnt vmcnt(0)"
                 : "=v"(a), "=v"(b) : "v"(f) : "memory");
    unsigned m = a[0];
    m = a[1] < m ? a[1] : m; m = a[2] < m ? a[2] : m; m = a[3] < m ? a[3] : m;
    m = b[0] < m ? b[0] : m; m = b[1] < m ? b[1] : m;
    m = b[2] < m ? b[2] : m; m = b[3] < m ? b[3] : m;
    if (m >= tgt) return;
    if (++gd > (1u << 18)) return;  // deadlock escape; never hit normally
  }
}

// flag init through the coherent path (hipMemset's cached zeros can evict OVER flags)
__global__ void k_initf(unsigned* __restrict__ f) {
  stflagc(f + threadIdx.x * 2, 0u);
  stflagc(f + threadIdx.x * 2 + 1, 0u);
}

// ---------------- fp32 -> bf16 converts ----------------
__global__ void k_f2b(const float* __restrict__ s, short* __restrict__ d, int n) {
  int i = (blockIdx.x * 256 + threadIdx.x) * 4;
  if (i >= n) return;
  float4 v = *(const float4*)(s + i);
  s16x4 o; o[0] = f2b(v.x); o[1] = f2b(v.y); o[2] = f2b(v.z); o[3] = f2b(v.w);
  *(s16x4*)(d + i) = o;
}
__global__ void k_f2bs(const float* __restrict__ s, short* __restrict__ d,
                       int cols, int sstr, int soff, int total) {
  int i = (blockIdx.x * 256 + threadIdx.x) * 4;
  if (i >= total) return;
  int r = i / cols, c = i - r * cols;
  float4 v = *(const float4*)(s + (size_t)r * sstr + soff + c);
  s16x4 o; o[0] = f2b(v.x); o[1] = f2b(v.y); o[2] = f2b(v.z); o[3] = f2b(v.w);
  *(s16x4*)(d + i) = o;
}
// merged decoder weights W_dec[2048][512]
__global__ void k_build_dec(const float* __restrict__ Whh, const float* __restrict__ Wih,
                            short* __restrict__ out) {
  int i = (blockIdx.x * 256 + threadIdx.x) * 4;
  if (i >= 1048576) return;
  int r = i >> 9, c = i & 511;
  float4 v;
  if (r < 1024) {
    float4 a = *(const float4*)(Whh + (size_t)r * 512 + c);
    float4 b = *(const float4*)(Wih + (size_t)r * 768 + 256 + c);
    v = make_float4(a.x + b.x, a.y + b.y, a.z + b.z, a.w + b.w);
  } else if (r < 1536) {
    v = *(const float4*)(Wih + (size_t)r * 768 + 256 + c);
  } else {
    v = *(const float4*)(Whh + (size_t)(r - 512) * 512 + c);
  }
  s16x4 o; o[0] = f2b(v.x); o[1] = f2b(v.y); o[2] = f2b(v.z); o[3] = f2b(v.w);
  *(s16x4*)(out + i) = o;
}

// ---------------- generic bf16 MFMA GEMM, 128x128 tile, BK=64 ----------------
// EPI: 0=f32, 1=relu->bf16, 3=tanh->f32 + plain bf16, 4=plain bf16 row-major
template <int EPI>
__global__ __launch_bounds__(256) void kgemm(
    const short* __restrict__ A, const short* __restrict__ W,
    const float* __restrict__ bias, float* __restrict__ outF,
    short* __restrict__ outB, int M, int N, int K) {
  __shared__ short lA[8192];
  __shared__ short lB[8192];
  const int tid = threadIdx.x, lane = tid & 63, wid = tid >> 6;
  const int l15 = lane & 15, lq = lane >> 4;
  const int m0 = blockIdx.x * 128, n0 = blockIdx.y * 128;
  const int wr2 = wid >> 1, wc2 = wid & 1;
  const f32x4 vz = {0.f, 0.f, 0.f, 0.f};
  f32x4 acc[4][4];
#pragma unroll
  for (int i = 0; i < 4; ++i)
#pragma unroll
    for (int j = 0; j < 4; ++j) acc[i][j] = vz;
  const int Kb = K * 2;
  const int nkt = K >> 6;
  const int srow = lane >> 3, sk = (lane & 7) * 16;
  const char* gA = (const char*)A;
  const char* gW = (const char*)W;
  for (int kt = 0; kt < nkt; ++kt) {
    __syncthreads();
#pragma unroll
    for (int i = 0; i < 4; ++i) {
      const int c = wid * 4 + i;
      gload16(gA + (size_t)(m0 + c * 8 + srow) * Kb + kt * 128 + sk, (char*)lA + c * 1024);
      gload16(gW + (size_t)(n0 + c * 8 + srow) * Kb + kt * 128 + sk, (char*)lB + c * 1024);
    }
    __syncthreads();
#pragma unroll
    for (int kc = 0; kc < 2; ++kc) {
      s16x8 af[4], bf[4];
#pragma unroll
      for (int mt = 0; mt < 4; ++mt)
        af[mt] = *(const s16x8*)((const char*)lA + (wr2 * 64 + mt * 16 + l15) * 128 + kc * 64 + lq * 16);
#pragma unroll
      for (int nt = 0; nt < 4; ++nt)
        bf[nt] = *(const s16x8*)((const char*)lB + (wc2 * 64 + nt * 16 + l15) * 128 + kc * 64 + lq * 16);
#pragma unroll
      for (int mt = 0; mt < 4; ++mt)
#pragma unroll
        for (int nt = 0; nt < 4; ++nt)
          acc[mt][nt] = MFMA(af[mt], bf[nt], acc[mt][nt]);
    }
  }
#pragma unroll
  for (int mt = 0; mt < 4; ++mt) {
#pragma unroll
    for (int nt = 0; nt < 4; ++nt) {
      const int col = n0 + wc2 * 64 + nt * 16 + l15;
      const int rl = wr2 * 64 + mt * 16 + lq * 4;
      const int row = m0 + rl;
      const float bv = bias ? bias[col] : 0.f;
      if (EPI == 0) {
#pragma unroll
        for (int d = 0; d < 4; ++d) outF[(size_t)(row + d) * N + col] = acc[mt][nt][d] + bv;
      } else if (EPI == 1) {
#pragma unroll
        for (int d = 0; d < 4; ++d) {
          float v = acc[mt][nt][d] + bv;
          v = v > 0.f ? v : 0.f;
          outB[(size_t)(row + d) * N + col] = f2b(v);
        }
      } else if (EPI == 3) {
#pragma unroll
        for (int d = 0; d < 4; ++d) {
          float v = ftanh(acc[mt][nt][d] + bv);
          outF[(size_t)(row + d) * N + col] = v;
          outB[(size_t)(row + d) * N + col] = f2b(v);
        }
      } else {  // EPI == 4: plain bf16 row-major
#pragma unroll
        for (int d = 0; d < 4; ++d)
          outB[(size_t)(row + d) * N + col] = f2b(acc[mt][nt][d] + bv);
      }
    }
  }
}

// ---------------- persistent encoder scan (round-12 structure; row-major xp) ----------------
// 128 WGs x 256 thr. WG w: gru=w>>6, rr=w&63, bg=rr>>3 (16 batches), cw=rr&7.
// Wave wid 0..3: cols J0=(cw*4+wid)*16. Sync groups: (gru,bg) x 8 col members.
// hB per gru: [2 parity][64 blk][128 b][8] bf16. xp row-major [24576][1536].
DEV void enc_xp_load(const short* xp, int tt, int J0, int lq, int b,
                     short xv[3][4]) {
  const short* xr = xp + (size_t)(tt * 128 + b) * 1536;
#pragma unroll
  for (int g = 0; g < 3; ++g)
#pragma unroll
    for (int d = 0; d < 4; ++d)
      xv[g][d] = xr[g * 512 + J0 + lq * 4 + d];
}

__global__ __launch_bounds__(256, 1) void enc_scan(
    const short* __restrict__ xpTf, const short* __restrict__ xpTb,
    const short* __restrict__ Whf, const short* __restrict__ Whb,
    const float* __restrict__ bhf, const float* __restrict__ bhb,
    short* __restrict__ hB, short* __restrict__ ench,
    unsigned* __restrict__ flags) {
  const int tid = threadIdx.x, lane = tid & 63, wid = tid >> 6;
  const int l15 = lane & 15, lq = lane >> 4;
  const int w = blockIdx.x;
  const int gru = w >> 6, rr = w & 63, bg = rr >> 3, cw = rr & 7;
  const int J0 = (cw * 4 + wid) * 16, b0 = bg * 16;
  const int b = b0 + l15;
  const short* Wg = gru ? Whb : Whf;
  const float* bb = gru ? bhb : bhf;
  const short* xpT = gru ? xpTb : xpTf;
  short* hBg = hB + (size_t)gru * 131072;
  unsigned* gfl = flags + (gru * 8 + bg) * 16;
  const f32x4 vz = {0.f, 0.f, 0.f, 0.f};

  s16x8 wfr[3][16];
#pragma unroll
  for (int g = 0; g < 3; ++g) {
    const short* wrp = Wg + (size_t)(g * 512 + J0 + l15) * 512 + lq * 8;
#pragma unroll
    for (int kc = 0; kc < 16; ++kc) wfr[g][kc] = *(const s16x8*)(wrp + kc * 32);
  }
  float bi[3][4];
#pragma unroll
  for (int g = 0; g < 3; ++g)
#pragma unroll
    for (int d = 0; d < 4; ++d) bi[g][d] = bb[g * 512 + J0 + lq * 4 + d];
  float hpv[4];
#pragma unroll
  for (int d = 0; d < 4; ++d) hpv[d] = 0.f;

  short xpv[3][4];
  enc_xp_load(xpT, gru ? 191 : 0, J0, lq, b, xpv);
  const int chb = J0 + lq * 4;

  // ---- t = 0 (peeled: h=0 -> acc=0) ----
  {
    s16x4 pk;
#pragma unroll
    for (int d = 0; d < 4; ++d) {
      float rg = fsig(b2f(xpv[0][d]) + bi[0][d]);
      float zg = fsig(b2f(xpv[1][d]) + bi[1][d]);
      float nn = ftanh(b2f(xpv[2][d]) + rg * bi[2][d]);
      float hv = (1.f - zg) * nn;
      hpv[d] = hv;
      pk[d] = f2b(hv);
    }
    st8c(hBg + (((size_t)((chb >> 3) * 128 + b)) << 3) + (chb & 7), pk);
    asm volatile("s_waitcnt vmcnt(0)" ::: "memory");
    __syncthreads();
    if (tid == 0) stflagc(gfl + cw, 1u);
    enc_xp_load(xpT, gru ? 190 : 1, J0, lq, b, xpv);  // xp(1), lands during poll
  }

  for (int t = 1; t < 192; ++t) {
    poll8c(gfl, (unsigned)t);
    s16x8 hb[16];
    const short* hsrc = hBg + ((t + 1) & 1) * 65536;
#pragma unroll
    for (int kc = 0; kc < 16; ++kc)
      hb[kc] = ld16c(hsrc + ((size_t)((kc * 4 + lq) * 128 + b) << 3));
    asm volatile("s_waitcnt vmcnt(0)" ::: "memory");
    __builtin_amdgcn_sched_barrier(0);
    f32x4 acc[3];
#pragma unroll
    for (int g = 0; g < 3; ++g) acc[g] = vz;
#pragma unroll
    for (int kc = 0; kc < 16; ++kc)
#pragma unroll
      for (int g = 0; g < 3; ++g) acc[g] = MFMA(wfr[g][kc], hb[kc], acc[g]);
    short* hdst = hBg + (t & 1) * 65536;
    s16x4 pk;
#pragma unroll
    for (int d = 0; d < 4; ++d) {
      float rg = fsig(b2f(xpv[0][d]) + acc[0][d] + bi[0][d]);
      float zg = fsig(b2f(xpv[1][d]) + acc[1][d] + bi[1][d]);
      float nn = ftanh(b2f(xpv[2][d]) + rg * (acc[2][d] + bi[2][d]));
      float hv = (1.f - zg) * nn + zg * hpv[d];
      hpv[d] = hv;
      pk[d] = f2b(hv);
    }
    st8c(hdst + (((size_t)((chb >> 3) * 128 + b)) << 3) + (chb & 7), pk);
    if (t == 191) *(s16x4*)(ench + (size_t)gru * 65536 + (size_t)b * 512 + chb) = pk;
    // drain only the h stores (xp prefetch is issued AFTER the flag, off the chain)
    asm volatile("s_waitcnt vmcnt(0)" ::: "memory");
    __syncthreads();
    if (tid == 0) stflagc(gfl + cw, (unsigned)(t + 1));
    if (t < 191) {
      const int tp = t + 1;
      enc_xp_load(xpT, gru ? (191 - tp) : tp, J0, lq, b, xpv);  // overlaps next poll
    }
  }
}

// ---------------- persistent decoder scan (merged weights; fixed roles, LLC) ----------------
// 64 WGs x 256 thr. bg = w>>3 (16 batches), m = w&7 (64 cols). 4 waves/WG.
// W_dec rows: [0..511]=merged r, [512..1023]=merged z, [1024..1535]=Ws_n, [1536..2047]=Whh_n.
// zp row-major [128][1536].
__global__ __launch_bounds__(256, 1) void dec_scan(
    const short* __restrict__ zpR, const short* __restrict__ Wd,
    const float* __restrict__ bhd, const float* __restrict__ pre0,
    const float* __restrict__ h0f, short* __restrict__ hB,
    short* __restrict__ Hs, unsigned* __restrict__ flags) {
  const int tid = threadIdx.x, lane = tid & 63, wid = tid >> 6;
  const int l15 = lane & 15, lq = lane >> 4;
  const int w = blockIdx.x;
  const int bg = w >> 3, m = w & 7;
  unsigned* gfl = flags + 256 + bg * 16;
  const int J0 = (m * 4 + wid) * 16, b0 = bg * 16;
  const int b = b0 + l15;
  const f32x4 vz = {0.f, 0.f, 0.f, 0.f};

  s16x8 wfr[4][16];
#pragma unroll
  for (int g = 0; g < 4; ++g) {
    const short* wrp = Wd + (size_t)(g * 512 + J0 + l15) * 512 + lq * 8;
#pragma unroll
    for (int kc = 0; kc < 16; ++kc) wfr[g][kc] = *(const s16x8*)(wrp + kc * 32);
  }
  float bi[3][4];
#pragma unroll
  for (int g = 0; g < 3; ++g)
#pragma unroll
    for (int d = 0; d < 4; ++d) bi[g][d] = bhd[g * 512 + J0 + lq * 4 + d];
  short zpv[3][4];
#pragma unroll
  for (int g = 0; g < 3; ++g)
#pragma unroll
    for (int d = 0; d < 4; ++d)
      zpv[g][d] = zpR[(size_t)b * 1536 + g * 512 + J0 + lq * 4 + d];
  float hpv[4];
#pragma unroll
  for (int d = 0; d < 4; ++d) hpv[d] = h0f[(size_t)b * 512 + J0 + lq * 4 + d];
  const int chb = J0 + lq * 4;

  // ---- t = 0 (peeled: s=0, h=dec_h0; pre0 = h0@Whh_d.T + bhh_d) ----
  {
    s16x4 pk;
#pragma unroll
    for (int d = 0; d < 4; ++d) {
      float p0 = pre0[(size_t)b * 1536 + 0 * 512 + J0 + lq * 4 + d];
      float p1 = pre0[(size_t)b * 1536 + 1 * 512 + J0 + lq * 4 + d];
      float p2 = pre0[(size_t)b * 1536 + 2 * 512 + J0 + lq * 4 + d];
      float rg = fsig(b2f(zpv[0][d]) + p0);
      float zg = fsig(b2f(zpv[1][d]) + p1);
      float nn = ftanh(b2f(zpv[2][d]) + rg * p2);
      float hv = (1.f - zg) * nn + zg * hpv[d];
      hpv[d] = hv;
      pk[d] = f2b(hv);
    }
    st8c(hB + (((size_t)((chb >> 3) * 128 + b)) << 3) + (chb & 7), pk);
    asm volatile("s_waitcnt vmcnt(0)" ::: "memory");
    __syncthreads();
    if (tid == 0) stflagc(gfl + m, 1u);
    *(s16x4*)(Hs + (size_t)b * 512 + chb) = pk;  // side-store, off the chain
  }

  for (int t = 1; t < 192; ++t) {
    poll8c(gfl, (unsigned)t);
    s16x8 hb[16];
    const short* hsrc = hB + ((t + 1) & 1) * 65536;
#pragma unroll
    for (int kc = 0; kc < 16; ++kc)
      hb[kc] = ld16c(hsrc + ((size_t)((kc * 4 + lq) * 128 + b) << 3));
    asm volatile("s_waitcnt vmcnt(0)" ::: "memory");
    __builtin_amdgcn_sched_barrier(0);
    f32x4 acc[4];
#pragma unroll
    for (int g = 0; g < 4; ++g) acc[g] = vz;
#pragma unroll
    for (int kc = 0; kc < 16; ++kc)
#pragma unroll
      for (int g = 0; g < 4; ++g) acc[g] = MFMA(wfr[g][kc], hb[kc], acc[g]);
    short* hdst = hB + (t & 1) * 65536;
    s16x4 pk;
#pragma unroll
    for (int d = 0; d < 4; ++d) {
      float rg = fsig(b2f(zpv[0][d]) + acc[0][d] + bi[0][d]);
      float zg = fsig(b2f(zpv[1][d]) + acc[1][d] + bi[1][d]);
      float nn = ftanh(b2f(zpv[2][d]) + acc[2][d] + rg * (acc[3][d] + bi[2][d]));
      float hv = (1.f - zg) * nn + zg * hpv[d];
      hpv[d] = hv;
      pk[d] = f2b(hv);
    }
    st8c(hdst + (((size_t)((chb >> 3) * 128 + b)) << 3) + (chb & 7), pk);
    asm volatile("s_waitcnt vmcnt(0)" ::: "memory");
    __syncthreads();
    if (tid == 0) stflagc(gfl + m, (unsigned)(t + 1));
    *(s16x4*)(Hs + (size_t)(t * 128 + b) * 512 + chb) = pk;  // off the chain
  }
}

// ---------------- latent elementwise ----------------
__global__ void k_latent(const float* __restrict__ tmp, const float* __restrict__ b_mean,
                         const float* __restrict__ b_std, const float* __restrict__ eps_z,
                         float* __restrict__ out, short* __restrict__ zexp) {
  int i = blockIdx.x * 256 + threadIdx.x;
  if (i >= 32768) return;
  int c = i & 127, b = (i >> 7) & 127, g = i >> 14;
  float mp = tmp[(size_t)(g * 128 + b) * 256 + c] + b_mean[c];
  float sp = fsp(tmp[(size_t)(g * 128 + b) * 256 + 128 + c] + b_std[c]);
  float zv = eps_z[i] * sp + mp;
  out[i] = mp;
  out[32768 + i] = sp;
  out[65536 + i] = zv;
  zexp[b * 256 + g * 128 + c] = f2b(zv);
}

// ---------------- outputs elementwise ----------------
__global__ void k_preds(const float* __restrict__ tmp2, const float* __restrict__ b_dm,
                        const float* __restrict__ b_ds, const float* __restrict__ eps_y,
                        float* __restrict__ out) {
  int j = blockIdx.x * 256 + threadIdx.x;
  if (j >= 1572864) return;
  int c = j & 63;
  int row = j >> 6;
  float m = fsp(tmp2[(size_t)row * 128 + c] + b_dm[c]);
  float st = fsp(tmp2[(size_t)row * 128 + 64 + c] + b_ds[c]);
  out[98304 + j] = eps_y[j] * st + m;
  out[1671168 + j] = m;
  out[3244032 + j] = st;
}

// ---------------- launch ----------------
extern "C" void kernel_launch(void* const* d_in, const int* in_sizes, int n_in,
                              void* d_out, int out_size, void* d_ws, size_t ws_size,
                              hipStream_t stream) {
  (void)in_sizes; (void)n_in; (void)out_size; (void)ws_size;
  const float* x      = (const float*)d_in[0];
  const float* eps_z  = (const float*)d_in[2];
  const float* eps_y  = (const float*)d_in[3];
  const float* W_phi1 = (const float*)d_in[4];
  const float* b_phi1 = (const float*)d_in[5];
  const float* W_phi2 = (const float*)d_in[6];
  const float* b_phi2 = (const float*)d_in[7];
  const float* Wih_ef = (const float*)d_in[8];
  const float* bih_ef = (const float*)d_in[9];
  const float* Whh_ef = (const float*)d_in[10];
  const float* bhh_ef = (const float*)d_in[11];
  const float* Wih_eb = (const float*)d_in[12];
  const float* bih_eb = (const float*)d_in[13];
  const float* Whh_eb = (const float*)d_in[14];
  const float* bhh_eb = (const float*)d_in[15];
  const float* W_mean = (const float*)d_in[16];
  const float* b_mean = (const float*)d_in[17];
  const float* W_std  = (const float*)d_in[18];
  const float* b_std  = (const float*)d_in[19];
  const float* W_fh   = (const float*)d_in[20];
  const float* b_fh   = (const float*)d_in[21];
  const float* Wih_d  = (const float*)d_in[22];
  const float* bih_d  = (const float*)d_in[23];
  const float* Whh_d  = (const float*)d_in[24];
  const float* bhh_d  = (const float*)d_in[25];
  const float* W_dm   = (const float*)d_in[26];
  const float* b_dm   = (const float*)d_in[27];
  const float* W_ds   = (const float*)d_in[28];
  const float* b_ds   = (const float*)d_in[29];
  float* out = (float*)d_out;
  char* ws = (char*)d_ws;

  short* x16  = (short*)(ws + 0);
  short* C1   = (short*)(ws + 6291456);
  short* Hs   = (short*)(ws + 0);
  short* phi  = (short*)(ws + 31457280);
  float* tmp2 = (float*)(ws + 31457280);
  short* xpf  = (short*)(ws + 56623104);
  short* xpb  = (short*)(ws + 132120576);
  short* w_dec = (short*)(ws + 56623104);
  float* pre0F = (float*)(ws + 58720256);
  short* h0b   = (short*)(ws + 59506688);
  char*  wb   = ws + 207618048;
  short* w_phi1_16 = (short*)(wb + 0);
  short* w_phi2_16 = (short*)(wb + 131072);
  short* w_ihef = (short*)(wb + 655360);
  short* w_hhef = (short*)(wb + 2228224);
  short* w_iheb = (short*)(wb + 3801088);
  short* w_hheb = (short*)(wb + 5373952);
  short* w_ms   = (short*)(wb + 6946816);
  short* w_fh   = (short*)(wb + 7208960);
  short* w_z    = (short*)(wb + 7471104);
  short* w_hhd  = (short*)(wb + 9830400);
  short* w_out  = (short*)(wb + 11403264);
  short* hBe   = (short*)(ws + 219152384);
  short* ench  = (short*)(ws + 219676672);
  float* tmpms = (float*)(ws + 219938816);
  short* zexp  = (short*)(ws + 220200960);
  float* h0f   = (float*)(ws + 220266496);
  short* hBd   = (short*)(ws + 220528640);
  short* zpR   = (short*)(ws + 220790784);
  unsigned* flags  = (unsigned*)(ws + 221184000);   // enc: [0..255], dec: [256..383]

  k_initf<<<1, 256, 0, stream>>>(flags);

  k_f2b<<<3072, 256, 0, stream>>>(x, x16, 3145728);
  k_f2b<<<64,   256, 0, stream>>>(W_phi1, w_phi1_16, 65536);
  k_f2b<<<256,  256, 0, stream>>>(W_phi2, w_phi2_16, 262144);
  k_f2b<<<768,  256, 0, stream>>>(Wih_ef, w_ihef, 786432);
  k_f2b<<<768,  256, 0, stream>>>(Whh_ef, w_hhef, 786432);
  k_f2b<<<768,  256, 0, stream>>>(Wih_eb, w_iheb, 786432);
  k_f2b<<<768,  256, 0, stream>>>(Whh_eb, w_hheb, 786432);
  k_f2b<<<64,   256, 0, stream>>>(W_mean, w_ms, 65536);
  k_f2b<<<64,   256, 0, stream>>>(W_std,  w_ms + 65536, 65536);
  k_f2b<<<128,  256, 0, stream>>>(W_fh, w_fh, 131072);
  k_f2b<<<768,  256, 0, stream>>>(Whh_d, w_hhd, 786432);
  k_f2b<<<32,   256, 0, stream>>>(W_dm, w_out, 32768);
  k_f2b<<<32,   256, 0, stream>>>(W_ds, w_out + 32768, 32768);
  k_f2bs<<<384, 256, 0, stream>>>(Wih_d, w_z, 256, 768, 0, 393216);

  kgemm<1><<<dim3(192, 4), 256, 0, stream>>>(x16, w_phi1_16, b_phi1, (float*)nullptr, C1, 24576, 512, 128);
  kgemm<1><<<dim3(192, 4), 256, 0, stream>>>(C1, w_phi2_16, b_phi2, (float*)nullptr, phi, 24576, 512, 512);
  kgemm<4><<<dim3(192, 12), 256, 0, stream>>>(phi, w_ihef, bih_ef, (float*)nullptr, xpf, 24576, 1536, 512);
  kgemm<4><<<dim3(192, 12), 256, 0, stream>>>(phi, w_iheb, bih_eb, (float*)nullptr, xpb, 24576, 1536, 512);
  enc_scan<<<128, 256, 0, stream>>>(xpf, xpb, w_hhef, w_hheb, bhh_ef, bhh_eb, hBe, ench, flags);
  // decoder prep (xpf region now dead)
  k_build_dec<<<1024, 256, 0, stream>>>(Whh_d, Wih_d, w_dec);
  kgemm<0><<<dim3(2, 2), 256, 0, stream>>>(ench, w_ms, (const float*)nullptr, tmpms, (short*)nullptr, 256, 256, 512);
  k_latent<<<128, 256, 0, stream>>>(tmpms, b_mean, b_std, eps_z, out, zexp);
  kgemm<3><<<dim3(1, 4), 256, 0, stream>>>(zexp, w_fh, b_fh, h0f, h0b, 128, 512, 256);
  kgemm<4><<<dim3(1, 12), 256, 0, stream>>>(zexp, w_z, bih_d, (float*)nullptr, zpR, 128, 1536, 256);
  kgemm<0><<<dim3(1, 12), 256, 0, stream>>>(h0b, w_hhd, bhh_d, pre0F, (short*)nullptr, 128, 1536, 512);
  dec_scan<<<64, 256, 0, stream>>>(zpR, w_dec, bhh_d, pre0F, h0f, hBd, Hs, flags);
  kgemm<0><<<dim3(192, 1), 256, 0, stream>>>(Hs, w_out, (const float*)nullptr, tmp2, (short*)nullptr, 24576, 128, 512);
  k_preds<<<6144, 256, 0, stream>>>(tmp2, b_dm, b_ds, eps_y, out);
}

// Round 15
// 1412.343 us; speedup vs baseline: 1.2489x; 1.1652x over previous
//
#include <hip/hip_runtime.h>
#include <stdint.h>

// ---------------- types & helpers ----------------
typedef __attribute__((ext_vector_type(4))) float    f32x4;
typedef __attribute__((ext_vector_type(8))) short    s16x8;
typedef __attribute__((ext_vector_type(4))) short    s16x4;
typedef __attribute__((ext_vector_type(4))) unsigned u32x4;
typedef __attribute__((ext_vector_type(8))) __bf16   bf16x8;

#define DEV __device__ __forceinline__

DEV float b2f(short h) {
  unsigned u = ((unsigned)(unsigned short)h) << 16;
  return __builtin_bit_cast(float, u);
}
DEV short f2b(float f) {
  unsigned u = __builtin_bit_cast(unsigned, f);
  u = (u + 0x7FFFu + ((u >> 16) & 1u)) >> 16;
  return (short)u;
}
DEV float fsig(float x) { return 1.0f / (1.0f + __expf(-x)); }
DEV float ftanh(float x) {
  x = fminf(fmaxf(x, -15.0f), 15.0f);
  float e = __expf(2.0f * x);
  return (e - 1.0f) / (e + 1.0f);
}
DEV float fsp(float x) { return (x > 20.0f) ? x : __logf(1.0f + __expf(x)); }

DEV f32x4 MFMA(s16x8 a, s16x8 b, f32x4 c) {
  return __builtin_amdgcn_mfma_f32_16x16x32_bf16(
      __builtin_bit_cast(bf16x8, a), __builtin_bit_cast(bf16x8, b), c, 0, 0, 0);
}
DEV void gload16(const void* g, void* l) {
  __builtin_amdgcn_global_load_lds(
      (const __attribute__((address_space(1))) unsigned*)g,
      (__attribute__((address_space(3))) unsigned*)l, 16, 0, 0);
}

// ---- cross-XCD coherent accesses via LLC: sc0 sc1 (bypass L1+L2) ----
DEV s16x8 ld16c(const short* p) {
  s16x8 r;
  asm volatile("global_load_dwordx4 %0, %1, off sc0 sc1" : "=v"(r) : "v"(p) : "memory");
  return r;
}
DEV void st8c(short* p, s16x4 v) {
  asm volatile("global_store_dwordx2 %0, %1, off sc0 sc1" :: "v"(p), "v"(v) : "memory");
}
DEV void stflagc(unsigned* p, unsigned v) {
  asm volatile("global_store_dword %0, %1, off sc0 sc1" :: "v"(p), "v"(v) : "memory");
}
// poll 8 flag dwords until min >= tgt
DEV void poll8c(const unsigned* f, unsigned tgt) {
  unsigned gd = 0;
  for (;;) {
    u32x4 a, b;
    asm volatile("global_load_dwordx4 %0, %2, off sc0 sc1\n\t"
                 "global_load_dwordx4 %1, %2, off offset:16 sc0 sc1\n\t"
                 "s_waitcnt vmcnt(0)"
                 : "=v"(a), "=v"(b) : "v"(f) : "memory");
    unsigned m = a[0];
    m = a[1] < m ? a[1] : m; m = a[2] < m ? a[2] : m; m = a[3] < m ? a[3] : m;
    m = b[0] < m ? b[0] : m; m = b[1] < m ? b[1] : m;
    m = b[2] < m ? b[2] : m; m = b[3] < m ? b[3] : m;
    if (m >= tgt) return;
    if (++gd > (1u << 18)) return;  // deadlock escape; never hit normally
  }
}

// flag init through the coherent path (hipMemset's cached zeros can evict OVER flags)
__global__ void k_initf(unsigned* __restrict__ f) {
  stflagc(f + threadIdx.x * 2, 0u);
  stflagc(f + threadIdx.x * 2 + 1, 0u);
}
// h-buffer init: fill cells with tag-1 pattern so first tag check (E=0) blocks
__global__ void k_inith(short* __restrict__ hBe, short* __restrict__ hBd) {
  int i = blockIdx.x * 256 + threadIdx.x;  // 16B cell index
  s16x4 v; v[0] = 1; v[1] = 1; v[2] = 1; v[3] = 1;
  if (i < 32768) {
    st8c(hBe + (size_t)i * 8, v);
    st8c(hBe + (size_t)i * 8 + 4, v);
  } else if (i < 49152) {
    int j = i - 32768;
    st8c(hBd + (size_t)j * 8, v);
    st8c(hBd + (size_t)j * 8 + 4, v);
  }
}

// ---------------- fp32 -> bf16 converts ----------------
__global__ void k_f2b(const float* __restrict__ s, short* __restrict__ d, int n) {
  int i = (blockIdx.x * 256 + threadIdx.x) * 4;
  if (i >= n) return;
  float4 v = *(const float4*)(s + i);
  s16x4 o; o[0] = f2b(v.x); o[1] = f2b(v.y); o[2] = f2b(v.z); o[3] = f2b(v.w);
  *(s16x4*)(d + i) = o;
}
__global__ void k_f2bs(const float* __restrict__ s, short* __restrict__ d,
                       int cols, int sstr, int soff, int total) {
  int i = (blockIdx.x * 256 + threadIdx.x) * 4;
  if (i >= total) return;
  int r = i / cols, c = i - r * cols;
  float4 v = *(const float4*)(s + (size_t)r * sstr + soff + c);
  s16x4 o; o[0] = f2b(v.x); o[1] = f2b(v.y); o[2] = f2b(v.z); o[3] = f2b(v.w);
  *(s16x4*)(d + i) = o;
}
// merged decoder weights W_dec[2048][512]
__global__ void k_build_dec(const float* __restrict__ Whh, const float* __restrict__ Wih,
                            short* __restrict__ out) {
  int i = (blockIdx.x * 256 + threadIdx.x) * 4;
  if (i >= 1048576) return;
  int r = i >> 9, c = i & 511;
  float4 v;
  if (r < 1024) {
    float4 a = *(const float4*)(Whh + (size_t)r * 512 + c);
    float4 b = *(const float4*)(Wih + (size_t)r * 768 + 256 + c);
    v = make_float4(a.x + b.x, a.y + b.y, a.z + b.z, a.w + b.w);
  } else if (r < 1536) {
    v = *(const float4*)(Wih + (size_t)r * 768 + 256 + c);
  } else {
    v = *(const float4*)(Whh + (size_t)(r - 512) * 512 + c);
  }
  s16x4 o; o[0] = f2b(v.x); o[1] = f2b(v.y); o[2] = f2b(v.z); o[3] = f2b(v.w);
  *(s16x4*)(out + i) = o;
}

// ---------------- generic bf16 MFMA GEMM, 128x128 tile, BK=64 ----------------
// EPI: 0=f32, 1=relu->bf16, 3=tanh->f32 + plain bf16, 4=plain bf16 row-major
template <int EPI>
__global__ __launch_bounds__(256) void kgemm(
    const short* __restrict__ A, const short* __restrict__ W,
    const float* __restrict__ bias, float* __restrict__ outF,
    short* __restrict__ outB, int M, int N, int K) {
  __shared__ short lA[8192];
  __shared__ short lB[8192];
  const int tid = threadIdx.x, lane = tid & 63, wid = tid >> 6;
  const int l15 = lane & 15, lq = lane >> 4;
  const int m0 = blockIdx.x * 128, n0 = blockIdx.y * 128;
  const int wr2 = wid >> 1, wc2 = wid & 1;
  const f32x4 vz = {0.f, 0.f, 0.f, 0.f};
  f32x4 acc[4][4];
#pragma unroll
  for (int i = 0; i < 4; ++i)
#pragma unroll
    for (int j = 0; j < 4; ++j) acc[i][j] = vz;
  const int Kb = K * 2;
  const int nkt = K >> 6;
  const int srow = lane >> 3, sk = (lane & 7) * 16;
  const char* gA = (const char*)A;
  const char* gW = (const char*)W;
  for (int kt = 0; kt < nkt; ++kt) {
    __syncthreads();
#pragma unroll
    for (int i = 0; i < 4; ++i) {
      const int c = wid * 4 + i;
      gload16(gA + (size_t)(m0 + c * 8 + srow) * Kb + kt * 128 + sk, (char*)lA + c * 1024);
      gload16(gW + (size_t)(n0 + c * 8 + srow) * Kb + kt * 128 + sk, (char*)lB + c * 1024);
    }
    __syncthreads();
#pragma unroll
    for (int kc = 0; kc < 2; ++kc) {
      s16x8 af[4], bf[4];
#pragma unroll
      for (int mt = 0; mt < 4; ++mt)
        af[mt] = *(const s16x8*)((const char*)lA + (wr2 * 64 + mt * 16 + l15) * 128 + kc * 64 + lq * 16);
#pragma unroll
      for (int nt = 0; nt < 4; ++nt)
        bf[nt] = *(const s16x8*)((const char*)lB + (wc2 * 64 + nt * 16 + l15) * 128 + kc * 64 + lq * 16);
#pragma unroll
      for (int mt = 0; mt < 4; ++mt)
#pragma unroll
        for (int nt = 0; nt < 4; ++nt)
          acc[mt][nt] = MFMA(af[mt], bf[nt], acc[mt][nt]);
    }
  }
#pragma unroll
  for (int mt = 0; mt < 4; ++mt) {
#pragma unroll
    for (int nt = 0; nt < 4; ++nt) {
      const int col = n0 + wc2 * 64 + nt * 16 + l15;
      const int rl = wr2 * 64 + mt * 16 + lq * 4;
      const int row = m0 + rl;
      const float bv = bias ? bias[col] : 0.f;
      if (EPI == 0) {
#pragma unroll
        for (int d = 0; d < 4; ++d) outF[(size_t)(row + d) * N + col] = acc[mt][nt][d] + bv;
      } else if (EPI == 1) {
#pragma unroll
        for (int d = 0; d < 4; ++d) {
          float v = acc[mt][nt][d] + bv;
          v = v > 0.f ? v : 0.f;
          outB[(size_t)(row + d) * N + col] = f2b(v);
        }
      } else if (EPI == 3) {
#pragma unroll
        for (int d = 0; d < 4; ++d) {
          float v = ftanh(acc[mt][nt][d] + bv);
          outF[(size_t)(row + d) * N + col] = v;
          outB[(size_t)(row + d) * N + col] = f2b(v);
        }
      } else {  // EPI == 4: plain bf16 row-major
#pragma unroll
        for (int d = 0; d < 4; ++d)
          outB[(size_t)(row + d) * N + col] = f2b(acc[mt][nt][d] + bv);
      }
    }
  }
}

// ---------------- persistent encoder scan (tag fast path + flag fallback) ----------------
// 128 WGs x 256 thr. WG w: gru=w>>6, rr=w&63, bg=rr>>3 (16 batches), cw=rr&7.
// hB cell = 16B; tag = LSB of shorts 0 and 4, generation (t>>1)&1. xp row-major.
DEV void enc_xp_load(const short* xp, int tt, int J0, int lq, int b,
                     short xv[3][4]) {
  const short* xr = xp + (size_t)(tt * 128 + b) * 1536;
#pragma unroll
  for (int g = 0; g < 3; ++g)
#pragma unroll
    for (int d = 0; d < 4; ++d)
      xv[g][d] = xr[g * 512 + J0 + lq * 4 + d];
}

__global__ __launch_bounds__(256, 1) void enc_scan(
    const short* __restrict__ xpTf, const short* __restrict__ xpTb,
    const short* __restrict__ Whf, const short* __restrict__ Whb,
    const float* __restrict__ bhf, const float* __restrict__ bhb,
    short* __restrict__ hB, short* __restrict__ ench,
    unsigned* __restrict__ flags) {
  const int tid = threadIdx.x, lane = tid & 63, wid = tid >> 6;
  const int l15 = lane & 15, lq = lane >> 4;
  const int w = blockIdx.x;
  const int gru = w >> 6, rr = w & 63, bg = rr >> 3, cw = rr & 7;
  const int J0 = (cw * 4 + wid) * 16, b0 = bg * 16;
  const int b = b0 + l15;
  const short* Wg = gru ? Whb : Whf;
  const float* bb = gru ? bhb : bhf;
  const short* xpT = gru ? xpTb : xpTf;
  short* hBg = hB + (size_t)gru * 131072;
  unsigned* gfl = flags + (gru * 8 + bg) * 16;
  const f32x4 vz = {0.f, 0.f, 0.f, 0.f};

  s16x8 wfr[3][16];
#pragma unroll
  for (int g = 0; g < 3; ++g) {
    const short* wrp = Wg + (size_t)(g * 512 + J0 + l15) * 512 + lq * 8;
#pragma unroll
    for (int kc = 0; kc < 16; ++kc) wfr[g][kc] = *(const s16x8*)(wrp + kc * 32);
  }
  float bi[3][4];
#pragma unroll
  for (int g = 0; g < 3; ++g)
#pragma unroll
    for (int d = 0; d < 4; ++d) bi[g][d] = bb[g * 512 + J0 + lq * 4 + d];
  float hpv[4];
#pragma unroll
  for (int d = 0; d < 4; ++d) hpv[d] = 0.f;

  short xpv[3][4];
  enc_xp_load(xpT, gru ? 191 : 0, J0, lq, b, xpv);
  const int chb = J0 + lq * 4;

  // ---- t = 0 (peeled: h=0 -> acc=0), output tag 0 ----
  {
    s16x4 pk;
#pragma unroll
    for (int d = 0; d < 4; ++d) {
      float rg = fsig(b2f(xpv[0][d]) + bi[0][d]);
      float zg = fsig(b2f(xpv[1][d]) + bi[1][d]);
      float nn = ftanh(b2f(xpv[2][d]) + rg * bi[2][d]);
      float hv = (1.f - zg) * nn;
      hpv[d] = hv;
      pk[d] = f2b(hv);
    }
    pk[0] = (short)(pk[0] & ~1);
    st8c(hBg + (((size_t)((chb >> 3) * 128 + b)) << 3) + (chb & 7), pk);
    asm volatile("s_waitcnt vmcnt(0)" ::: "memory");
    __syncthreads();
    if (tid == 0) stflagc(gfl + cw, 1u);
    enc_xp_load(xpT, gru ? 190 : 1, J0, lq, b, xpv);  // xp(1), lands during poll
  }

  for (int t = 1; t < 192; ++t) {
    const int E = ((t - 1) >> 1) & 1;  // expected tag of inputs
    const int T = (t >> 1) & 1;        // tag for our outputs
    const short* hsrc = hBg + ((t + 1) & 1) * 65536;
    s16x8 hb[16];
    // fast path: tag-validated loads (freshness + data in ONE LLC round trip)
    bool fresh = false;
    for (int it = 0; it < 24; ++it) {
#pragma unroll
      for (int kc = 0; kc < 16; ++kc)
        hb[kc] = ld16c(hsrc + ((size_t)((kc * 4 + lq) * 128 + b) << 3));
      asm volatile("s_waitcnt vmcnt(0)" ::: "memory");
      unsigned ok = 1u;
#pragma unroll
      for (int kc = 0; kc < 16; ++kc)
        ok &= (unsigned)((hb[kc][0] & 1) == E) & (unsigned)((hb[kc][4] & 1) == E);
      if (__all((int)ok)) { fresh = true; break; }
    }
    if (!fresh) {  // fallback: proven flag path
      poll8c(gfl, (unsigned)t);
#pragma unroll
      for (int kc = 0; kc < 16; ++kc)
        hb[kc] = ld16c(hsrc + ((size_t)((kc * 4 + lq) * 128 + b) << 3));
      asm volatile("s_waitcnt vmcnt(0)" ::: "memory");
    }
    __builtin_amdgcn_sched_barrier(0);
    f32x4 acc[3];
#pragma unroll
    for (int g = 0; g < 3; ++g) acc[g] = vz;
#pragma unroll
    for (int kc = 0; kc < 16; ++kc)
#pragma unroll
      for (int g = 0; g < 3; ++g) acc[g] = MFMA(wfr[g][kc], hb[kc], acc[g]);
    short* hdst = hBg + (t & 1) * 65536;
    s16x4 pk;
#pragma unroll
    for (int d = 0; d < 4; ++d) {
      float rg = fsig(b2f(xpv[0][d]) + acc[0][d] + bi[0][d]);
      float zg = fsig(b2f(xpv[1][d]) + acc[1][d] + bi[1][d]);
      float nn = ftanh(b2f(xpv[2][d]) + rg * (acc[2][d] + bi[2][d]));
      float hv = (1.f - zg) * nn + zg * hpv[d];
      hpv[d] = hv;
      pk[d] = f2b(hv);
    }
    pk[0] = (short)((pk[0] & ~1) | T);
    st8c(hdst + (((size_t)((chb >> 3) * 128 + b)) << 3) + (chb & 7), pk);
    if (t == 191) *(s16x4*)(ench + (size_t)gru * 65536 + (size_t)b * 512 + chb) = pk;
    asm volatile("s_waitcnt vmcnt(0)" ::: "memory");
    __syncthreads();
    if (tid == 0) stflagc(gfl + cw, (unsigned)(t + 1));
    if (t < 191) {
      const int tp = t + 1;
      enc_xp_load(xpT, gru ? (191 - tp) : tp, J0, lq, b, xpv);  // overlaps next poll
    }
  }
}

// ---------------- persistent decoder scan (merged weights; tag fast path) ----------------
// 64 WGs x 256 thr. bg = w>>3 (16 batches), m = w&7 (64 cols). 4 waves/WG.
__global__ __launch_bounds__(256, 1) void dec_scan(
    const short* __restrict__ zpR, const short* __restrict__ Wd,
    const float* __restrict__ bhd, const float* __restrict__ pre0,
    const float* __restrict__ h0f, short* __restrict__ hB,
    short* __restrict__ Hs, unsigned* __restrict__ flags) {
  const int tid = threadIdx.x, lane = tid & 63, wid = tid >> 6;
  const int l15 = lane & 15, lq = lane >> 4;
  const int w = blockIdx.x;
  const int bg = w >> 3, m = w & 7;
  unsigned* gfl = flags + 256 + bg * 16;
  const int J0 = (m * 4 + wid) * 16, b0 = bg * 16;
  const int b = b0 + l15;
  const f32x4 vz = {0.f, 0.f, 0.f, 0.f};

  s16x8 wfr[4][16];
#pragma unroll
  for (int g = 0; g < 4; ++g) {
    const short* wrp = Wd + (size_t)(g * 512 + J0 + l15) * 512 + lq * 8;
#pragma unroll
    for (int kc = 0; kc < 16; ++kc) wfr[g][kc] = *(const s16x8*)(wrp + kc * 32);
  }
  float bi[3][4];
#pragma unroll
  for (int g = 0; g < 3; ++g)
#pragma unroll
    for (int d = 0; d < 4; ++d) bi[g][d] = bhd[g * 512 + J0 + lq * 4 + d];
  short zpv[3][4];
#pragma unroll
  for (int g = 0; g < 3; ++g)
#pragma unroll
    for (int d = 0; d < 4; ++d)
      zpv[g][d] = zpR[(size_t)b * 1536 + g * 512 + J0 + lq * 4 + d];
  float hpv[4];
#pragma unroll
  for (int d = 0; d < 4; ++d) hpv[d] = h0f[(size_t)b * 512 + J0 + lq * 4 + d];
  const int chb = J0 + lq * 4;

  // ---- t = 0 (peeled: s=0, h=dec_h0; pre0 = h0@Whh_d.T + bhh_d), tag 0 ----
  {
    s16x4 pk;
#pragma unroll
    for (int d = 0; d < 4; ++d) {
      float p0 = pre0[(size_t)b * 1536 + 0 * 512 + J0 + lq * 4 + d];
      float p1 = pre0[(size_t)b * 1536 + 1 * 512 + J0 + lq * 4 + d];
      float p2 = pre0[(size_t)b * 1536 + 2 * 512 + J0 + lq * 4 + d];
      float rg = fsig(b2f(zpv[0][d]) + p0);
      float zg = fsig(b2f(zpv[1][d]) + p1);
      float nn = ftanh(b2f(zpv[2][d]) + rg * p2);
      float hv = (1.f - zg) * nn + zg * hpv[d];
      hpv[d] = hv;
      pk[d] = f2b(hv);
    }
    pk[0] = (short)(pk[0] & ~1);
    st8c(hB + (((size_t)((chb >> 3) * 128 + b)) << 3) + (chb & 7), pk);
    asm volatile("s_waitcnt vmcnt(0)" ::: "memory");
    __syncthreads();
    if (tid == 0) stflagc(gfl + m, 1u);
    *(s16x4*)(Hs + (size_t)b * 512 + chb) = pk;  // side-store, off the chain
  }

  for (int t = 1; t < 192; ++t) {
    const int E = ((t - 1) >> 1) & 1;
    const int T = (t >> 1) & 1;
    const short* hsrc = hB + ((t + 1) & 1) * 65536;
    s16x8 hb[16];
    bool fresh = false;
    for (int it = 0; it < 24; ++it) {
#pragma unroll
      for (int kc = 0; kc < 16; ++kc)
        hb[kc] = ld16c(hsrc + ((size_t)((kc * 4 + lq) * 128 + b) << 3));
      asm volatile("s_waitcnt vmcnt(0)" ::: "memory");
      unsigned ok = 1u;
#pragma unroll
      for (int kc = 0; kc < 16; ++kc)
        ok &= (unsigned)((hb[kc][0] & 1) == E) & (unsigned)((hb[kc][4] & 1) == E);
      if (__all((int)ok)) { fresh = true; break; }
    }
    if (!fresh) {
      poll8c(gfl, (unsigned)t);
#pragma unroll
      for (int kc = 0; kc < 16; ++kc)
        hb[kc] = ld16c(hsrc + ((size_t)((kc * 4 + lq) * 128 + b) << 3));
      asm volatile("s_waitcnt vmcnt(0)" ::: "memory");
    }
    __builtin_amdgcn_sched_barrier(0);
    f32x4 acc[4];
#pragma unroll
    for (int g = 0; g < 4; ++g) acc[g] = vz;
#pragma unroll
    for (int kc = 0; kc < 16; ++kc)
#pragma unroll
      for (int g = 0; g < 4; ++g) acc[g] = MFMA(wfr[g][kc], hb[kc], acc[g]);
    short* hdst = hB + (t & 1) * 65536;
    s16x4 pk;
#pragma unroll
    for (int d = 0; d < 4; ++d) {
      float rg = fsig(b2f(zpv[0][d]) + acc[0][d] + bi[0][d]);
      float zg = fsig(b2f(zpv[1][d]) + acc[1][d] + bi[1][d]);
      float nn = ftanh(b2f(zpv[2][d]) + acc[2][d] + rg * (acc[3][d] + bi[2][d]));
      float hv = (1.f - zg) * nn + zg * hpv[d];
      hpv[d] = hv;
      pk[d] = f2b(hv);
    }
    pk[0] = (short)((pk[0] & ~1) | T);
    st8c(hdst + (((size_t)((chb >> 3) * 128 + b)) << 3) + (chb & 7), pk);
    asm volatile("s_waitcnt vmcnt(0)" ::: "memory");
    __syncthreads();
    if (tid == 0) stflagc(gfl + m, (unsigned)(t + 1));
    *(s16x4*)(Hs + (size_t)(t * 128 + b) * 512 + chb) = pk;  // off the chain
  }
}

// ---------------- latent elementwise ----------------
__global__ void k_latent(const float* __restrict__ tmp, const float* __restrict__ b_mean,
                         const float* __restrict__ b_std, const float* __restrict__ eps_z,
                         float* __restrict__ out, short* __restrict__ zexp) {
  int i = blockIdx.x * 256 + threadIdx.x;
  if (i >= 32768) return;
  int c = i & 127, b = (i >> 7) & 127, g = i >> 14;
  float mp = tmp[(size_t)(g * 128 + b) * 256 + c] + b_mean[c];
  float sp = fsp(tmp[(size_t)(g * 128 + b) * 256 + 128 + c] + b_std[c]);
  float zv = eps_z[i] * sp + mp;
  out[i] = mp;
  out[32768 + i] = sp;
  out[65536 + i] = zv;
  zexp[b * 256 + g * 128 + c] = f2b(zv);
}

// ---------------- outputs elementwise ----------------
__global__ void k_preds(const float* __restrict__ tmp2, const float* __restrict__ b_dm,
                        const float* __restrict__ b_ds, const float* __restrict__ eps_y,
                        float* __restrict__ out) {
  int j = blockIdx.x * 256 + threadIdx.x;
  if (j >= 1572864) return;
  int c = j & 63;
  int row = j >> 6;
  float m = fsp(tmp2[(size_t)row * 128 + c] + b_dm[c]);
  float st = fsp(tmp2[(size_t)row * 128 + 64 + c] + b_ds[c]);
  out[98304 + j] = eps_y[j] * st + m;
  out[1671168 + j] = m;
  out[3244032 + j] = st;
}

// ---------------- launch ----------------
extern "C" void kernel_launch(void* const* d_in, const int* in_sizes, int n_in,
                              void* d_out, int out_size, void* d_ws, size_t ws_size,
                              hipStream_t stream) {
  (void)in_sizes; (void)n_in; (void)out_size; (void)ws_size;
  const float* x      = (const float*)d_in[0];
  const float* eps_z  = (const float*)d_in[2];
  const float* eps_y  = (const float*)d_in[3];
  const float* W_phi1 = (const float*)d_in[4];
  const float* b_phi1 = (const float*)d_in[5];
  const float* W_phi2 = (const float*)d_in[6];
  const float* b_phi2 = (const float*)d_in[7];
  const float* Wih_ef = (const float*)d_in[8];
  const float* bih_ef = (const float*)d_in[9];
  const float* Whh_ef = (const float*)d_in[10];
  const float* bhh_ef = (const float*)d_in[11];
  const float* Wih_eb = (const float*)d_in[12];
  const float* bih_eb = (const float*)d_in[13];
  const float* Whh_eb = (const float*)d_in[14];
  const float* bhh_eb = (const float*)d_in[15];
  const float* W_mean = (const float*)d_in[16];
  const float* b_mean = (const float*)d_in[17];
  const float* W_std  = (const float*)d_in[18];
  const float* b_std  = (const float*)d_in[19];
  const float* W_fh   = (const float*)d_in[20];
  const float* b_fh   = (const float*)d_in[21];
  const float* Wih_d  = (const float*)d_in[22];
  const float* bih_d  = (const float*)d_in[23];
  const float* Whh_d  = (const float*)d_in[24];
  const float* bhh_d  = (const float*)d_in[25];
  const float* W_dm   = (const float*)d_in[26];
  const float* b_dm   = (const float*)d_in[27];
  const float* W_ds   = (const float*)d_in[28];
  const float* b_ds   = (const float*)d_in[29];
  float* out = (float*)d_out;
  char* ws = (char*)d_ws;

  short* x16  = (short*)(ws + 0);
  short* C1   = (short*)(ws + 6291456);
  short* Hs   = (short*)(ws + 0);
  short* phi  = (short*)(ws + 31457280);
  float* tmp2 = (float*)(ws + 31457280);
  short* xpf  = (short*)(ws + 56623104);
  short* xpb  = (short*)(ws + 132120576);
  short* w_dec = (short*)(ws + 56623104);
  float* pre0F = (float*)(ws + 58720256);
  short* h0b   = (short*)(ws + 59506688);
  char*  wb   = ws + 207618048;
  short* w_phi1_16 = (short*)(wb + 0);
  short* w_phi2_16 = (short*)(wb + 131072);
  short* w_ihef = (short*)(wb + 655360);
  short* w_hhef = (short*)(wb + 2228224);
  short* w_iheb = (short*)(wb + 3801088);
  short* w_hheb = (short*)(wb + 5373952);
  short* w_ms   = (short*)(wb + 6946816);
  short* w_fh   = (short*)(wb + 7208960);
  short* w_z    = (short*)(wb + 7471104);
  short* w_hhd  = (short*)(wb + 9830400);
  short* w_out  = (short*)(wb + 11403264);
  short* hBe   = (short*)(ws + 219152384);
  short* ench  = (short*)(ws + 219676672);
  float* tmpms = (float*)(ws + 219938816);
  short* zexp  = (short*)(ws + 220200960);
  float* h0f   = (float*)(ws + 220266496);
  short* hBd   = (short*)(ws + 220528640);
  short* zpR   = (short*)(ws + 220790784);
  unsigned* flags  = (unsigned*)(ws + 221184000);   // enc: [0..255], dec: [256..383]

  k_initf<<<1, 256, 0, stream>>>(flags);
  k_inith<<<192, 256, 0, stream>>>(hBe, hBd);

  k_f2b<<<3072, 256, 0, stream>>>(x, x16, 3145728);
  k_f2b<<<64,   256, 0, stream>>>(W_phi1, w_phi1_16, 65536);
  k_f2b<<<256,  256, 0, stream>>>(W_phi2, w_phi2_16, 262144);
  k_f2b<<<768,  256, 0, stream>>>(Wih_ef, w_ihef, 786432);
  k_f2b<<<768,  256, 0, stream>>>(Whh_ef, w_hhef, 786432);
  k_f2b<<<768,  256, 0, stream>>>(Wih_eb, w_iheb, 786432);
  k_f2b<<<768,  256, 0, stream>>>(Whh_eb, w_hheb, 786432);
  k_f2b<<<64,   256, 0, stream>>>(W_mean, w_ms, 65536);
  k_f2b<<<64,   256, 0, stream>>>(W_std,  w_ms + 65536, 65536);
  k_f2b<<<128,  256, 0, stream>>>(W_fh, w_fh, 131072);
  k_f2b<<<768,  256, 0, stream>>>(Whh_d, w_hhd, 786432);
  k_f2b<<<32,   256, 0, stream>>>(W_dm, w_out, 32768);
  k_f2b<<<32,   256, 0, stream>>>(W_ds, w_out + 32768, 32768);
  k_f2bs<<<384, 256, 0, stream>>>(Wih_d, w_z, 256, 768, 0, 393216);

  kgemm<1><<<dim3(192, 4), 256, 0, stream>>>(x16, w_phi1_16, b_phi1, (float*)nullptr, C1, 24576, 512, 128);
  kgemm<1><<<dim3(192, 4), 256, 0, stream>>>(C1, w_phi2_16, b_phi2, (float*)nullptr, phi, 24576, 512, 512);
  kgemm<4><<<dim3(192, 12), 256, 0, stream>>>(phi, w_ihef, bih_ef, (float*)nullptr, xpf, 24576, 1536, 512);
  kgemm<4><<<dim3(192, 12), 256, 0, stream>>>(phi, w_iheb, bih_eb, (float*)nullptr, xpb, 24576, 1536, 512);
  enc_scan<<<128, 256, 0, stream>>>(xpf, xpb, w_hhef, w_hheb, bhh_ef, bhh_eb, hBe, ench, flags);
  // decoder prep (xpf region now dead)
  k_build_dec<<<1024, 256, 0, stream>>>(Whh_d, Wih_d, w_dec);
  kgemm<0><<<dim3(2, 2), 256, 0, stream>>>(ench, w_ms, (const float*)nullptr, tmpms, (short*)nullptr, 256, 256, 512);
  k_latent<<<128, 256, 0, stream>>>(tmpms, b_mean, b_std, eps_z, out, zexp);
  kgemm<3><<<dim3(1, 4), 256, 0, stream>>>(zexp, w_fh, b_fh, h0f, h0b, 128, 512, 256);
  kgemm<4><<<dim3(1, 12), 256, 0, stream>>>(zexp, w_z, bih_d, (float*)nullptr, zpR, 128, 1536, 256);
  kgemm<0><<<dim3(1, 12), 256, 0, stream>>>(h0b, w_hhd, bhh_d, pre0F, (short*)nullptr, 128, 1536, 512);
  dec_scan<<<64, 256, 0, stream>>>(zpR, w_dec, bhh_d, pre0F, h0f, hBd, Hs, flags);
  kgemm<0><<<dim3(192, 1), 256, 0, stream>>>(Hs, w_out, (const float*)nullptr, tmp2, (short*)nullptr, 24576, 128, 512);
  k_preds<<<6144, 256, 0, stream>>>(tmp2, b_dm, b_ds, eps_y, out);
}